// Round 2
// baseline (464.544 us; speedup 1.0000x reference)
//
#include <hip/hip_runtime.h>
#include <hip/hip_bf16.h>
#include <stdint.h>

// MultiHeadAttention: x[4,2048,1024] fp32, mask[4,2048] i32,
// w_qkv[3072,1024], w_tail[1024,1024], b_tail[1024] -> out[4,2048,1024] fp32
// Pipeline: cvt->bf16, GEMM1 (qkv proj; Q,K -> [bh][t][d], V -> [bh][d][t]),
// flash attention (swizzled LDS, conflict-free), GEMM2 (+bias, fp32 out).

typedef __attribute__((ext_vector_type(8))) short short8;
typedef __attribute__((ext_vector_type(4))) float f32x4;

#define T_SEQ 2048
#define NHEAD 16
#define DHEAD 64
#define DMODEL 1024

__device__ __forceinline__ ushort f2bf(float f) {
  uint32_t u = __float_as_uint(f);
  uint32_t r = (u + 0x7FFFu + ((u >> 16) & 1u)) >> 16;
  return (ushort)r;
}
__device__ __forceinline__ float bf2f(ushort b) {
  return __uint_as_float(((uint32_t)b) << 16);
}

__device__ __forceinline__ void gload_lds16(const ushort* g, ushort* l) {
  __builtin_amdgcn_global_load_lds(
      (const __attribute__((address_space(1))) void*)g,
      (__attribute__((address_space(3))) void*)l, 16, 0, 0);
}

// ---------------- fp32 -> bf16 conversion ----------------
__global__ void cvt_f32_bf16(const float* __restrict__ in,
                             ushort* __restrict__ out, int n8) {
  int i = blockIdx.x * blockDim.x + threadIdx.x;
  if (i < n8) {
    const float4* p = (const float4*)(in + (size_t)i * 8);
    float4 a = p[0], b = p[1];
    short8 o;
    o[0] = (short)f2bf(a.x); o[1] = (short)f2bf(a.y);
    o[2] = (short)f2bf(a.z); o[3] = (short)f2bf(a.w);
    o[4] = (short)f2bf(b.x); o[5] = (short)f2bf(b.y);
    o[6] = (short)f2bf(b.z); o[7] = (short)f2bf(b.w);
    *(short8*)(out + (size_t)i * 8) = o;
  }
}

// ---------------- bf16 GEMM: C = A * B^T ----------------
// A [M][K] bf16 row-major, B [N][K] bf16 row-major (both K-contiguous).
// 128x128 tile, BK=64, 4 waves (2x2), each wave 64x64 via 4x4 16x16x32 MFMA.
// EPI==0: scatter-store bf16 qkv: Q,K -> [bh][t][64]; V -> [bh][64][t] (transposed)
// EPI==1: fp32 store to Cout[M][N] + bias
template <int EPI>
__launch_bounds__(256)
__global__ void gemm_bt(const ushort* __restrict__ A,
                        const ushort* __restrict__ B,
                        void* __restrict__ Cout,
                        const float* __restrict__ bias,
                        int M, int N, int K) {
  __shared__ ushort sA[128 * 64];
  __shared__ ushort sB[128 * 64];
  const int tid = threadIdx.x;
  const int lane = tid & 63;
  const int wid = tid >> 6;
  const int wr = wid >> 1, wc = wid & 1;
  const int bm = blockIdx.x * 128;
  const int bn = blockIdx.y * 128;
  const int l15 = lane & 15;
  const int lg = lane >> 4;

  f32x4 acc[4][4] = {};

  for (int k0 = 0; k0 < K; k0 += 64) {
#pragma unroll
    for (int r = 0; r < 4; ++r) {
      int c = r * 256 + tid;
      int row = c >> 3, ci = c & 7;
      gload_lds16(A + (size_t)(bm + row) * K + k0 + ci * 8, sA + c * 8);
      gload_lds16(B + (size_t)(bn + row) * K + k0 + ci * 8, sB + c * 8);
    }
    __syncthreads();
#pragma unroll
    for (int ks = 0; ks < 2; ++ks) {
      short8 af[4], bfr[4];
#pragma unroll
      for (int m = 0; m < 4; ++m)
        af[m] = *(const short8*)&sA[(wr * 64 + m * 16 + l15) * 64 + ks * 32 + lg * 8];
#pragma unroll
      for (int n = 0; n < 4; ++n)
        bfr[n] = *(const short8*)&sB[(wc * 64 + n * 16 + l15) * 64 + ks * 32 + lg * 8];
#pragma unroll
      for (int m = 0; m < 4; ++m)
#pragma unroll
        for (int n = 0; n < 4; ++n)
          acc[m][n] = __builtin_amdgcn_mfma_f32_16x16x32_bf16(af[m], bfr[n], acc[m][n], 0, 0, 0);
    }
    __syncthreads();
  }

  if (EPI == 0) {
    ushort* qkvb = (ushort*)Cout;
#pragma unroll
    for (int m = 0; m < 4; ++m)
#pragma unroll
      for (int n = 0; n < 4; ++n)
#pragma unroll
        for (int r = 0; r < 4; ++r) {
          int gr = bm + wr * 64 + m * 16 + lg * 4 + r;  // = b*T + t
          int gc = bn + wc * 64 + n * 16 + l15;         // o in [0,3072)
          int b = gr >> 11, t = gr & (T_SEQ - 1);
          int h = gc / 192, rem = gc - h * 192;
          int sel = rem >> 6, d = rem & 63;
          size_t base = (size_t)((b * NHEAD + h) * 3 + sel) * T_SEQ * DHEAD;
          size_t dst = (sel == 2) ? base + (size_t)d * T_SEQ + t     // V transposed [d][t]
                                  : base + (size_t)t * DHEAD + d;    // Q,K [t][d]
          qkvb[dst] = f2bf(acc[m][n][r]);
        }
  } else {
    float* out = (float*)Cout;
#pragma unroll
    for (int m = 0; m < 4; ++m)
#pragma unroll
      for (int n = 0; n < 4; ++n) {
        int gc = bn + wc * 64 + n * 16 + l15;
        float bv = bias[gc];
#pragma unroll
        for (int r = 0; r < 4; ++r) {
          int gr = bm + wr * 64 + m * 16 + lg * 4 + r;
          out[(size_t)gr * N + gc] = acc[m][n][r] + bv;
        }
      }
  }
}

// ---------------- flash attention ----------------
// qkv layout: Q,K = [bh*3+{0,1}][2048][64]; V^T = [bh*3+2][64][2048] bf16.
// Block: 256 threads (4 waves), each wave 32 q rows -> QBLK=128. KBLK=64.
// All LDS tiles XOR-swizzled (T2): phys 16B-block = logical block ^ (row&7).
// K/V^T staged via global_load_lds with pre-swizzled global source (rule #21).
// Output attn bf16 [b*2048+t][h*64+d].
__launch_bounds__(256)
__global__ void attn_fwd(const ushort* __restrict__ qkv,
                         const int* __restrict__ mask,
                         ushort* __restrict__ attn) {
  __shared__ ushort sK[64 * 64];
  __shared__ ushort sVT[64 * 64];   // [d][k] rows=d
  __shared__ ushort sP[4][32 * 64];

  const int tid = threadIdx.x;
  const int lane = tid & 63;
  const int wid = tid >> 6;
  const int l15 = lane & 15;
  const int lg = lane >> 4;
  const int swz = (l15 & 7) << 3;  // ushort-index XOR for fragment reads
  const int qt = blockIdx.x;   // 0..15
  const int bh = blockIdx.y;   // 0..63
  const int b = bh >> 4, h = bh & 15;

  const ushort* Qp  = qkv + (size_t)(bh * 3 + 0) * T_SEQ * DHEAD;
  const ushort* Kp  = qkv + (size_t)(bh * 3 + 1) * T_SEQ * DHEAD;
  const ushort* VTp = qkv + (size_t)(bh * 3 + 2) * T_SEQ * DHEAD;  // [64][2048]
  const int* mrow = mask + b * T_SEQ;

  const int qbase = qt * 128 + wid * 32;

  // Q fragments, pre-scaled by 0.125 (exact exponent shift in bf16)
  short8 qf[2][2];
#pragma unroll
  for (int m = 0; m < 2; ++m)
#pragma unroll
    for (int ks = 0; ks < 2; ++ks) {
      short8 raw = *(const short8*)&Qp[(size_t)(qbase + m * 16 + l15) * 64 + ks * 32 + lg * 8];
#pragma unroll
      for (int e = 0; e < 8; ++e)
        qf[m][ks][e] = (short)f2bf(bf2f((ushort)raw[e]) * 0.125f);
    }

  float mrun[2][4], lrun[2][4];
#pragma unroll
  for (int m = 0; m < 2; ++m)
#pragma unroll
    for (int r = 0; r < 4; ++r) { mrun[m][r] = -1e30f; lrun[m][r] = 0.f; }
  f32x4 oacc[2][4] = {};

  for (int kt = 0; kt < T_SEQ / 64; ++kt) {
    const int kb = kt * 64;
    // stage K [64 k][64 d] and V^T [64 d][64 k], both linear-dest,
    // source column-block pre-swizzled: src_blk = ci ^ (row&7)
#pragma unroll
    for (int r = 0; r < 2; ++r) {
      int c = r * 256 + tid;
      int row = c >> 3, ci = c & 7;
      int sb = (ci ^ (row & 7)) * 8;
      gload_lds16(Kp + (size_t)(kb + row) * 64 + sb, sK + c * 8);
      gload_lds16(VTp + (size_t)row * T_SEQ + kb + sb, sVT + c * 8);
    }
    __syncthreads();

    // S = (Q/8) K^T  (per wave: 32x64)
    f32x4 sacc[2][4] = {};
#pragma unroll
    for (int ks = 0; ks < 2; ++ks) {
      short8 kf[4];
#pragma unroll
      for (int n = 0; n < 4; ++n)
        kf[n] = *(const short8*)&sK[(n * 16 + l15) * 64 + ((ks * 32 + lg * 8) ^ swz)];
#pragma unroll
      for (int m = 0; m < 2; ++m)
#pragma unroll
        for (int n = 0; n < 4; ++n)
          sacc[m][n] = __builtin_amdgcn_mfma_f32_16x16x32_bf16(qf[m][ks], kf[n], sacc[m][n], 0, 0, 0);
    }

    // mask (key mask, same for every query row)
    int keep[4];
#pragma unroll
    for (int n = 0; n < 4; ++n) keep[n] = mrow[kb + n * 16 + l15];
#pragma unroll
    for (int m = 0; m < 2; ++m)
#pragma unroll
      for (int n = 0; n < 4; ++n)
        if (!keep[n])
#pragma unroll
          for (int r = 0; r < 4; ++r) sacc[m][n][r] = -1e30f;

    // online softmax per (m, reg) row; row spread over 16-lane group
#pragma unroll
    for (int m = 0; m < 2; ++m) {
      float tmax[4];
#pragma unroll
      for (int r = 0; r < 4; ++r) {
        float v = sacc[m][0][r];
#pragma unroll
        for (int n = 1; n < 4; ++n) v = fmaxf(v, sacc[m][n][r]);
        tmax[r] = v;
      }
#pragma unroll
      for (int off = 1; off < 16; off <<= 1)
#pragma unroll
        for (int r = 0; r < 4; ++r) tmax[r] = fmaxf(tmax[r], __shfl_xor(tmax[r], off));

      float alpha[4], rsum[4];
#pragma unroll
      for (int r = 0; r < 4; ++r) {
        float mn = fmaxf(mrun[m][r], tmax[r]);
        alpha[r] = __expf(mrun[m][r] - mn);
        mrun[m][r] = mn;
        rsum[r] = 0.f;
      }
#pragma unroll
      for (int n = 0; n < 4; ++n)
#pragma unroll
        for (int r = 0; r < 4; ++r) {
          float p = __expf(sacc[m][n][r] - mrun[m][r]);
          sacc[m][n][r] = p;
          rsum[r] += p;
        }
#pragma unroll
      for (int off = 1; off < 16; off <<= 1)
#pragma unroll
        for (int r = 0; r < 4; ++r) rsum[r] += __shfl_xor(rsum[r], off);
#pragma unroll
      for (int r = 0; r < 4; ++r) lrun[m][r] = lrun[m][r] * alpha[r] + rsum[r];
#pragma unroll
      for (int dt = 0; dt < 4; ++dt)
#pragma unroll
        for (int r = 0; r < 4; ++r) oacc[m][dt][r] *= alpha[r];
      // P -> per-wave LDS (C-layout -> A-layout refragmentation), swizzled
#pragma unroll
      for (int n = 0; n < 4; ++n)
#pragma unroll
        for (int r = 0; r < 4; ++r) {
          int row = m * 16 + lg * 4 + r;
          int col = n * 16 + l15;
          sP[wid][row * 64 + (col ^ ((row & 7) << 3))] = f2bf(sacc[m][n][r]);
        }
    }

    // O += P V   (A = P from sP, B = V^T rows = d), swizzled reads
#pragma unroll
    for (int ks = 0; ks < 2; ++ks) {
      short8 pf[2];
#pragma unroll
      for (int m = 0; m < 2; ++m)
        pf[m] = *(const short8*)&sP[wid][(m * 16 + l15) * 64 + ((ks * 32 + lg * 8) ^ swz)];
#pragma unroll
      for (int dt = 0; dt < 4; ++dt) {
        short8 vf = *(const short8*)&sVT[(dt * 16 + l15) * 64 + ((ks * 32 + lg * 8) ^ swz)];
#pragma unroll
        for (int m = 0; m < 2; ++m)
          oacc[m][dt] = __builtin_amdgcn_mfma_f32_16x16x32_bf16(pf[m], vf, oacc[m][dt], 0, 0, 0);
      }
    }
    __syncthreads();
  }

  // epilogue: attn[b*T+t][h*64+d] = O / l
#pragma unroll
  for (int m = 0; m < 2; ++m) {
    float rl[4];
#pragma unroll
    for (int r = 0; r < 4; ++r) rl[r] = 1.0f / lrun[m][r];
#pragma unroll
    for (int dt = 0; dt < 4; ++dt)
#pragma unroll
      for (int r = 0; r < 4; ++r) {
        int t = qbase + m * 16 + lg * 4 + r;
        int d = dt * 16 + l15;
        attn[(size_t)(b * T_SEQ + t) * DMODEL + h * DHEAD + d] = f2bf(oacc[m][dt][r] * rl[r]);
      }
  }
}

// ---------------- launch ----------------
extern "C" void kernel_launch(void* const* d_in, const int* in_sizes, int n_in,
                              void* d_out, int out_size, void* d_ws, size_t ws_size,
                              hipStream_t stream) {
  (void)in_sizes; (void)n_in; (void)out_size; (void)ws_size;
  const float* x      = (const float*)d_in[0];  // [4,2048,1024]
  const int*   mask   = (const int*)d_in[1];    // [4,2048]
  const float* w_qkv  = (const float*)d_in[2];  // [3072,1024]
  const float* w_tail = (const float*)d_in[3];  // [1024,1024]
  const float* b_tail = (const float*)d_in[4];  // [1024]
  float* out = (float*)d_out;

  const size_t M = 4 * 2048;
  ushort* xb     = (ushort*)d_ws;                    // 8192*1024
  ushort* wqkvb  = xb + M * DMODEL;                  // 3072*1024
  ushort* wtailb = wqkvb + 3 * DMODEL * DMODEL;      // 1024*1024
  ushort* qkvb   = wtailb + DMODEL * DMODEL;         // 64*3*2048*64
  ushort* attnb  = qkvb + (size_t)64 * 3 * T_SEQ * DHEAD;  // 8192*1024

  {
    int n8 = (int)(M * DMODEL / 8);
    cvt_f32_bf16<<<n8 / 256, 256, 0, stream>>>(x, xb, n8);
  }
  {
    int n8 = 3 * DMODEL * DMODEL / 8;
    cvt_f32_bf16<<<n8 / 256, 256, 0, stream>>>(w_qkv, wqkvb, n8);
  }
  {
    int n8 = DMODEL * DMODEL / 8;
    cvt_f32_bf16<<<n8 / 256, 256, 0, stream>>>(w_tail, wtailb, n8);
  }

  // GEMM1: qkv = x @ w_qkv^T ; scatter Q,K [t][d], V [d][t]
  gemm_bt<0><<<dim3(M / 128, 3 * DMODEL / 128), 256, 0, stream>>>(
      xb, wqkvb, qkvb, nullptr, (int)M, 3 * DMODEL, DMODEL);

  // attention
  attn_fwd<<<dim3(T_SEQ / 128, 64), 256, 0, stream>>>(qkvb, mask, attnb);

  // GEMM2: out = attn @ w_tail^T + b_tail (fp32 out)
  gemm_bt<1><<<dim3(M / 128, DMODEL / 128), 256, 0, stream>>>(
      attnb, wtailb, out, b_tail, (int)M, DMODEL, DMODEL);
}

// Round 3
// 303.358 us; speedup vs baseline: 1.5313x; 1.5313x over previous
//
#include <hip/hip_runtime.h>
#include <hip/hip_bf16.h>
#include <stdint.h>

// MultiHeadAttention: x[4,2048,1024] fp32, mask[4,2048] i32,
// w_qkv[3072,1024], w_tail[1024,1024], b_tail[1024] -> out[4,2048,1024] fp32
// Pipeline: cvt->bf16, GEMM1 (qkv proj; Q,K -> [bh][t][d], V -> [bh][d][t]),
// flash attention (swapped-QK^T, in-register P, dbuf staging), GEMM2 (+bias).

typedef __attribute__((ext_vector_type(8))) short short8;
typedef __attribute__((ext_vector_type(4))) short short4b;
typedef __attribute__((ext_vector_type(4))) float f32x4;

#define T_SEQ 2048
#define NHEAD 16
#define DHEAD 64
#define DMODEL 1024

__device__ __forceinline__ ushort f2bf(float f) {
  uint32_t u = __float_as_uint(f);
  uint32_t r = (u + 0x7FFFu + ((u >> 16) & 1u)) >> 16;
  return (ushort)r;
}
__device__ __forceinline__ float bf2f(ushort b) {
  return __uint_as_float(((uint32_t)b) << 16);
}

__device__ __forceinline__ void gload_lds16(const ushort* g, ushort* l) {
  __builtin_amdgcn_global_load_lds(
      (const __attribute__((address_space(1))) void*)g,
      (__attribute__((address_space(3))) void*)l, 16, 0, 0);
}

// ---------------- fp32 -> bf16 conversion ----------------
__global__ void cvt_f32_bf16(const float* __restrict__ in,
                             ushort* __restrict__ out, int n8) {
  int i = blockIdx.x * blockDim.x + threadIdx.x;
  if (i < n8) {
    const float4* p = (const float4*)(in + (size_t)i * 8);
    float4 a = p[0], b = p[1];
    short8 o;
    o[0] = (short)f2bf(a.x); o[1] = (short)f2bf(a.y);
    o[2] = (short)f2bf(a.z); o[3] = (short)f2bf(a.w);
    o[4] = (short)f2bf(b.x); o[5] = (short)f2bf(b.y);
    o[6] = (short)f2bf(b.z); o[7] = (short)f2bf(b.w);
    *(short8*)(out + (size_t)i * 8) = o;
  }
}

// ---------------- bf16 GEMM: C = A * B^T ----------------
// (unchanged from round 2)
template <int EPI>
__launch_bounds__(256)
__global__ void gemm_bt(const ushort* __restrict__ A,
                        const ushort* __restrict__ B,
                        void* __restrict__ Cout,
                        const float* __restrict__ bias,
                        int M, int N, int K) {
  __shared__ ushort sA[128 * 64];
  __shared__ ushort sB[128 * 64];
  const int tid = threadIdx.x;
  const int lane = tid & 63;
  const int wid = tid >> 6;
  const int wr = wid >> 1, wc = wid & 1;
  const int bm = blockIdx.x * 128;
  const int bn = blockIdx.y * 128;
  const int l15 = lane & 15;
  const int lg = lane >> 4;

  f32x4 acc[4][4] = {};

  for (int k0 = 0; k0 < K; k0 += 64) {
#pragma unroll
    for (int r = 0; r < 4; ++r) {
      int c = r * 256 + tid;
      int row = c >> 3, ci = c & 7;
      gload_lds16(A + (size_t)(bm + row) * K + k0 + ci * 8, sA + c * 8);
      gload_lds16(B + (size_t)(bn + row) * K + k0 + ci * 8, sB + c * 8);
    }
    __syncthreads();
#pragma unroll
    for (int ks = 0; ks < 2; ++ks) {
      short8 af[4], bfr[4];
#pragma unroll
      for (int m = 0; m < 4; ++m)
        af[m] = *(const short8*)&sA[(wr * 64 + m * 16 + l15) * 64 + ks * 32 + lg * 8];
#pragma unroll
      for (int n = 0; n < 4; ++n)
        bfr[n] = *(const short8*)&sB[(wc * 64 + n * 16 + l15) * 64 + ks * 32 + lg * 8];
#pragma unroll
      for (int m = 0; m < 4; ++m)
#pragma unroll
        for (int n = 0; n < 4; ++n)
          acc[m][n] = __builtin_amdgcn_mfma_f32_16x16x32_bf16(af[m], bfr[n], acc[m][n], 0, 0, 0);
    }
    __syncthreads();
  }

  if (EPI == 0) {
    ushort* qkvb = (ushort*)Cout;
#pragma unroll
    for (int m = 0; m < 4; ++m)
#pragma unroll
      for (int n = 0; n < 4; ++n)
#pragma unroll
        for (int r = 0; r < 4; ++r) {
          int gr = bm + wr * 64 + m * 16 + lg * 4 + r;  // = b*T + t
          int gc = bn + wc * 64 + n * 16 + l15;         // o in [0,3072)
          int b = gr >> 11, t = gr & (T_SEQ - 1);
          int h = gc / 192, rem = gc - h * 192;
          int sel = rem >> 6, d = rem & 63;
          size_t base = (size_t)((b * NHEAD + h) * 3 + sel) * T_SEQ * DHEAD;
          size_t dst = (sel == 2) ? base + (size_t)d * T_SEQ + t     // V^T [d][t]
                                  : base + (size_t)t * DHEAD + d;    // Q,K [t][d]
          qkvb[dst] = f2bf(acc[m][n][r]);
        }
  } else {
    float* out = (float*)Cout;
#pragma unroll
    for (int m = 0; m < 4; ++m)
#pragma unroll
      for (int n = 0; n < 4; ++n) {
        int gc = bn + wc * 64 + n * 16 + l15;
        float bv = bias[gc];
#pragma unroll
        for (int r = 0; r < 4; ++r) {
          int gr = bm + wr * 64 + m * 16 + lg * 4 + r;
          out[(size_t)gr * N + gc] = acc[m][n][r] + bv;
        }
      }
  }
}

// ---------------- flash attention (swapped QK^T, in-register P) ------------
// qkv: Q,K = [bh*3+{0,1}][2048][64]; V^T = [bh*3+2][64][2048] bf16.
// 256 threads / 4 waves, 32 q-rows per wave (QBLK=128), KVBLK=64, dbuf LDS.
// S^T = mfma(K,Q): lane holds S[q=l15][kv=n*16+lg*4+r] -> softmax row ops are
// in-register (+2 shfl_xor). P stays in registers via k-slot bijection
// sigma(lg,e) = (e>>2)*16+lg*4+(e&3) applied to BOTH PV operands.
// PV = mfma(V,P) -> O^T (col=q=l15) so stats need no cross-lane transpose.
__launch_bounds__(256)
__global__ void attn_fwd(const ushort* __restrict__ qkv,
                         const int* __restrict__ mask,
                         ushort* __restrict__ attn) {
  __shared__ ushort sK[2][64 * 64];
  __shared__ ushort sVT[2][64 * 64];   // [d][kv] rows=d, 16B-chunk XOR swizzle

  const int tid = threadIdx.x;
  const int lane = tid & 63;
  const int wid = tid >> 6;
  const int l15 = lane & 15;
  const int lg = lane >> 4;
  const int qt = blockIdx.x;   // 0..15
  const int bh = blockIdx.y;   // 0..63
  const int b = bh >> 4, h = bh & 15;

  const ushort* Qp  = qkv + (size_t)(bh * 3 + 0) * T_SEQ * DHEAD;
  const ushort* Kp  = qkv + (size_t)(bh * 3 + 1) * T_SEQ * DHEAD;
  const ushort* VTp = qkv + (size_t)(bh * 3 + 2) * T_SEQ * DHEAD;  // [64][2048]
  const int* mrow = mask + b * T_SEQ;

  const int qbase = qt * 128 + wid * 32;

  // Q fragments, pre-scaled by 0.125 (exact exponent shift in bf16)
  short8 qf[2][2];
#pragma unroll
  for (int m = 0; m < 2; ++m)
#pragma unroll
    for (int ks = 0; ks < 2; ++ks) {
      short8 raw = *(const short8*)&Qp[(size_t)(qbase + m * 16 + l15) * 64 + ks * 32 + lg * 8];
#pragma unroll
      for (int e = 0; e < 8; ++e)
        qf[m][ks][e] = (short)f2bf(bf2f((ushort)raw[e]) * 0.125f);
    }

  float mrun[2] = {-1e30f, -1e30f};
  float lrun[2] = {0.f, 0.f};
  f32x4 oacc[2][4] = {};   // [m][dt] = O^T tile: row d=dt*16+lg*4+r, col q=m*16+l15

  auto STAGE = [&](int buf, int kt) {
    const int kb = kt * 64;
#pragma unroll
    for (int r2 = 0; r2 < 2; ++r2) {
      int c = r2 * 256 + tid;
      int row = c >> 3, ci = c & 7;
      int sb = (ci ^ (row & 7)) * 8;   // 16B-chunk source pre-swizzle
      gload_lds16(Kp + (size_t)(kb + row) * 64 + sb, &sK[buf][c * 8]);
      gload_lds16(VTp + (size_t)row * T_SEQ + kb + sb, &sVT[buf][c * 8]);
    }
  };

  STAGE(0, 0);
  __syncthreads();

  const int NT = T_SEQ / 64;
  for (int kt = 0; kt < NT; ++kt) {
    const int cur = kt & 1;
    int mv = mrow[kt * 64 + lane];          // issued early, consumed post-QK
    if (kt + 1 < NT) STAGE(cur ^ 1, kt + 1);

    // S^T = K (Q/8)^T : st[n][m], lane holds S[q=l15][kv = n*16+lg*4+r]
    f32x4 st[4][2] = {};
#pragma unroll
    for (int ks = 0; ks < 2; ++ks) {
      short8 kf[4];
#pragma unroll
      for (int n = 0; n < 4; ++n)
        kf[n] = *(const short8*)&sK[cur][(n * 16 + l15) * 64 + ((ks * 4 + lg) ^ (l15 & 7)) * 8];
#pragma unroll
      for (int n = 0; n < 4; ++n)
#pragma unroll
        for (int m = 0; m < 2; ++m)
          st[n][m] = __builtin_amdgcn_mfma_f32_16x16x32_bf16(kf[n], qf[m][ks], st[n][m], 0, 0, 0);
    }

    // key mask via wave bitmap
    unsigned long long km = __ballot(mv != 0);
#pragma unroll
    for (int n = 0; n < 4; ++n) {
      uint32_t k4 = (uint32_t)(km >> (n * 16 + lg * 4)) & 0xFu;
#pragma unroll
      for (int m = 0; m < 2; ++m)
#pragma unroll
        for (int r = 0; r < 4; ++r)
          if (!(k4 & (1u << r))) st[n][m][r] = -1e30f;
    }

    // online softmax: per-lane row (q=l15), 15 fmax + 2 shfl per reduce
#pragma unroll
    for (int m = 0; m < 2; ++m) {
      float mx = st[0][m][0];
#pragma unroll
      for (int n = 0; n < 4; ++n)
#pragma unroll
        for (int r = 0; r < 4; ++r)
          if (n | r) mx = fmaxf(mx, st[n][m][r]);
      mx = fmaxf(mx, __shfl_xor(mx, 16, 64));
      mx = fmaxf(mx, __shfl_xor(mx, 32, 64));
      float mn = fmaxf(mrun[m], mx);
      float alpha = __expf(mrun[m] - mn);
      mrun[m] = mn;
      float rs = 0.f;
#pragma unroll
      for (int n = 0; n < 4; ++n)
#pragma unroll
        for (int r = 0; r < 4; ++r) {
          float p = __expf(st[n][m][r] - mn);
          st[n][m][r] = p;
          rs += p;
        }
      rs += __shfl_xor(rs, 16, 64);
      rs += __shfl_xor(rs, 32, 64);
      lrun[m] = lrun[m] * alpha + rs;
#pragma unroll
      for (int dt = 0; dt < 4; ++dt)
#pragma unroll
        for (int r = 0; r < 4; ++r) oacc[m][dt][r] *= alpha;
    }

    // pack P -> bf16 A/B-frag (k-slot sigma: e<4 -> n=ks*2, e>=4 -> n=ks*2+1)
    short8 pa[2][2];
#pragma unroll
    for (int m = 0; m < 2; ++m)
#pragma unroll
      for (int ks = 0; ks < 2; ++ks)
#pragma unroll
        for (int e = 0; e < 4; ++e) {
          pa[m][ks][e]     = (short)f2bf(st[ks * 2][m][e]);
          pa[m][ks][4 + e] = (short)f2bf(st[ks * 2 + 1][m][e]);
        }

    // O^T += V^T * P^T : A = V-frag (rows d), B = P-frag (cols q)
#pragma unroll
    for (int ks = 0; ks < 2; ++ks)
#pragma unroll
      for (int dt = 0; dt < 4; ++dt) {
        const int row = dt * 16 + l15;
        // logical ushort off = ks*32 + h*16 + lg*4 ; 16B chunk = ks*4+h*2+(lg>>1)
        const short4b v0 = *(const short4b*)&sVT[cur][row * 64 +
            (((ks * 4 + 0 + (lg >> 1)) ^ (l15 & 7)) * 8) + (lg & 1) * 4];
        const short4b v1 = *(const short4b*)&sVT[cur][row * 64 +
            (((ks * 4 + 2 + (lg >> 1)) ^ (l15 & 7)) * 8) + (lg & 1) * 4];
        short8 vf;
        vf[0] = v0[0]; vf[1] = v0[1]; vf[2] = v0[2]; vf[3] = v0[3];
        vf[4] = v1[0]; vf[5] = v1[1]; vf[6] = v1[2]; vf[7] = v1[3];
#pragma unroll
        for (int m = 0; m < 2; ++m)
          oacc[m][dt] = __builtin_amdgcn_mfma_f32_16x16x32_bf16(vf, pa[m][ks], oacc[m][dt], 0, 0, 0);
      }
    __syncthreads();
  }

  // epilogue: O^T layout -> packed 8B stores (d contiguous over r)
#pragma unroll
  for (int m = 0; m < 2; ++m) {
    float rl = 1.0f / lrun[m];
    int t = qbase + m * 16 + l15;
#pragma unroll
    for (int dt = 0; dt < 4; ++dt) {
      short4b ov;
#pragma unroll
      for (int r = 0; r < 4; ++r) ov[r] = (short)f2bf(oacc[m][dt][r] * rl);
      *(short4b*)&attn[(size_t)(b * T_SEQ + t) * DMODEL + h * DHEAD + dt * 16 + lg * 4] = ov;
    }
  }
}

// ---------------- launch ----------------
extern "C" void kernel_launch(void* const* d_in, const int* in_sizes, int n_in,
                              void* d_out, int out_size, void* d_ws, size_t ws_size,
                              hipStream_t stream) {
  (void)in_sizes; (void)n_in; (void)out_size; (void)ws_size;
  const float* x      = (const float*)d_in[0];  // [4,2048,1024]
  const int*   mask   = (const int*)d_in[1];    // [4,2048]
  const float* w_qkv  = (const float*)d_in[2];  // [3072,1024]
  const float* w_tail = (const float*)d_in[3];  // [1024,1024]
  const float* b_tail = (const float*)d_in[4];  // [1024]
  float* out = (float*)d_out;

  const size_t M = 4 * 2048;
  ushort* xb     = (ushort*)d_ws;                    // 8192*1024
  ushort* wqkvb  = xb + M * DMODEL;                  // 3072*1024
  ushort* wtailb = wqkvb + 3 * DMODEL * DMODEL;      // 1024*1024
  ushort* qkvb   = wtailb + DMODEL * DMODEL;         // 64*3*2048*64
  ushort* attnb  = qkvb + (size_t)64 * 3 * T_SEQ * DHEAD;  // 8192*1024

  {
    int n8 = (int)(M * DMODEL / 8);
    cvt_f32_bf16<<<n8 / 256, 256, 0, stream>>>(x, xb, n8);
  }
  {
    int n8 = 3 * DMODEL * DMODEL / 8;
    cvt_f32_bf16<<<n8 / 256, 256, 0, stream>>>(w_qkv, wqkvb, n8);
  }
  {
    int n8 = DMODEL * DMODEL / 8;
    cvt_f32_bf16<<<n8 / 256, 256, 0, stream>>>(w_tail, wtailb, n8);
  }

  // GEMM1: qkv = x @ w_qkv^T ; scatter Q,K [t][d], V [d][t]
  gemm_bt<0><<<dim3(M / 128, 3 * DMODEL / 128), 256, 0, stream>>>(
      xb, wqkvb, qkvb, nullptr, (int)M, 3 * DMODEL, DMODEL);

  // attention
  attn_fwd<<<dim3(T_SEQ / 128, 64), 256, 0, stream>>>(qkvb, mask, attnb);

  // GEMM2: out = attn @ w_tail^T + b_tail (fp32 out)
  gemm_bt<1><<<dim3(M / 128, DMODEL / 128), 256, 0, stream>>>(
      attnb, wtailb, out, b_tail, (int)M, DMODEL, DMODEL);
}

// Round 4
// 264.229 us; speedup vs baseline: 1.7581x; 1.1481x over previous
//
#include <hip/hip_runtime.h>
#include <hip/hip_bf16.h>
#include <stdint.h>

// MultiHeadAttention: x[4,2048,1024] fp32, mask[4,2048] i32,
// w_qkv[3072,1024], w_tail[1024,1024], b_tail[1024] -> out[4,2048,1024] fp32
// Pipeline: cvt->bf16, GEMM1 (qkv proj; Q,K -> [bh][t][d], V -> [bh][d][t]),
// flash attention (swapped-QK^T, in-register P, exp2-domain softmax,
// defer-max, native cvt_pk bf16 packing, setprio), GEMM2 (+bias).

typedef __attribute__((ext_vector_type(8))) short short8;
typedef __attribute__((ext_vector_type(4))) short short4b;
typedef __attribute__((ext_vector_type(4))) float f32x4;

#define T_SEQ 2048
#define NHEAD 16
#define DHEAD 64
#define DMODEL 1024

#if __has_builtin(__builtin_amdgcn_exp2f)
#define EXP2(x) __builtin_amdgcn_exp2f(x)
#else
#define EXP2(x) exp2f(x)
#endif

// native converts -> v_cvt_pk_bf16_f32 (RNE); do NOT hand-write bit math (m240)
__device__ __forceinline__ ushort f2bf(float f) {
  __bf16 h = (__bf16)f;
  unsigned short u;
  __builtin_memcpy(&u, &h, 2);
  return u;
}
__device__ __forceinline__ float bf2f(ushort b) {
  return __uint_as_float(((uint32_t)b) << 16);
}

__device__ __forceinline__ void gload_lds16(const ushort* g, ushort* l) {
  __builtin_amdgcn_global_load_lds(
      (const __attribute__((address_space(1))) void*)g,
      (__attribute__((address_space(3))) void*)l, 16, 0, 0);
}

// ---------------- fp32 -> bf16 conversion ----------------
__global__ void cvt_f32_bf16(const float* __restrict__ in,
                             ushort* __restrict__ out, int n8) {
  int i = blockIdx.x * blockDim.x + threadIdx.x;
  if (i < n8) {
    const float4* p = (const float4*)(in + (size_t)i * 8);
    float4 a = p[0], b = p[1];
    short8 o;
    o[0] = (short)f2bf(a.x); o[1] = (short)f2bf(a.y);
    o[2] = (short)f2bf(a.z); o[3] = (short)f2bf(a.w);
    o[4] = (short)f2bf(b.x); o[5] = (short)f2bf(b.y);
    o[6] = (short)f2bf(b.z); o[7] = (short)f2bf(b.w);
    *(short8*)(out + (size_t)i * 8) = o;
  }
}

// ---------------- bf16 GEMM: C = A * B^T ----------------
// (structure unchanged; epilogue converts via native cast)
template <int EPI>
__launch_bounds__(256)
__global__ void gemm_bt(const ushort* __restrict__ A,
                        const ushort* __restrict__ B,
                        void* __restrict__ Cout,
                        const float* __restrict__ bias,
                        int M, int N, int K) {
  __shared__ ushort sA[128 * 64];
  __shared__ ushort sB[128 * 64];
  const int tid = threadIdx.x;
  const int lane = tid & 63;
  const int wid = tid >> 6;
  const int wr = wid >> 1, wc = wid & 1;
  const int bm = blockIdx.x * 128;
  const int bn = blockIdx.y * 128;
  const int l15 = lane & 15;
  const int lg = lane >> 4;

  f32x4 acc[4][4] = {};

  for (int k0 = 0; k0 < K; k0 += 64) {
#pragma unroll
    for (int r = 0; r < 4; ++r) {
      int c = r * 256 + tid;
      int row = c >> 3, ci = c & 7;
      gload_lds16(A + (size_t)(bm + row) * K + k0 + ci * 8, sA + c * 8);
      gload_lds16(B + (size_t)(bn + row) * K + k0 + ci * 8, sB + c * 8);
    }
    __syncthreads();
#pragma unroll
    for (int ks = 0; ks < 2; ++ks) {
      short8 af[4], bfr[4];
#pragma unroll
      for (int m = 0; m < 4; ++m)
        af[m] = *(const short8*)&sA[(wr * 64 + m * 16 + l15) * 64 + ks * 32 + lg * 8];
#pragma unroll
      for (int n = 0; n < 4; ++n)
        bfr[n] = *(const short8*)&sB[(wc * 64 + n * 16 + l15) * 64 + ks * 32 + lg * 8];
      __builtin_amdgcn_s_setprio(1);
#pragma unroll
      for (int m = 0; m < 4; ++m)
#pragma unroll
        for (int n = 0; n < 4; ++n)
          acc[m][n] = __builtin_amdgcn_mfma_f32_16x16x32_bf16(af[m], bfr[n], acc[m][n], 0, 0, 0);
      __builtin_amdgcn_s_setprio(0);
    }
    __syncthreads();
  }

  if (EPI == 0) {
    ushort* qkvb = (ushort*)Cout;
#pragma unroll
    for (int m = 0; m < 4; ++m)
#pragma unroll
      for (int n = 0; n < 4; ++n)
#pragma unroll
        for (int r = 0; r < 4; ++r) {
          int gr = bm + wr * 64 + m * 16 + lg * 4 + r;  // = b*T + t
          int gc = bn + wc * 64 + n * 16 + l15;         // o in [0,3072)
          int b = gr >> 11, t = gr & (T_SEQ - 1);
          int h = gc / 192, rem = gc - h * 192;
          int sel = rem >> 6, d = rem & 63;
          size_t base = (size_t)((b * NHEAD + h) * 3 + sel) * T_SEQ * DHEAD;
          size_t dst = (sel == 2) ? base + (size_t)d * T_SEQ + t     // V^T [d][t]
                                  : base + (size_t)t * DHEAD + d;    // Q,K [t][d]
          qkvb[dst] = f2bf(acc[m][n][r]);
        }
  } else {
    float* out = (float*)Cout;
#pragma unroll
    for (int m = 0; m < 4; ++m)
#pragma unroll
      for (int n = 0; n < 4; ++n) {
        int gc = bn + wc * 64 + n * 16 + l15;
        float bv = bias[gc];
#pragma unroll
        for (int r = 0; r < 4; ++r) {
          int gr = bm + wr * 64 + m * 16 + lg * 4 + r;
          out[(size_t)gr * N + gc] = acc[m][n][r] + bv;
        }
      }
  }
}

// ---------------- flash attention (swapped QK^T, in-register P) ------------
// qkv: Q,K = [bh*3+{0,1}][2048][64]; V^T = [bh*3+2][64][2048] bf16.
// 256 threads / 4 waves, 32 q-rows per wave (QBLK=128), KVBLK=64, dbuf LDS.
// S^T = mfma(K, Q*0.125*log2e): lane holds S2[q=l15][kv=n*16+lg*4+r] in log2
// units -> softmax rows in-register (+2 shfl_xor), p = exp2(s2-m2) directly.
// P stays in registers via k-slot bijection applied to BOTH PV operands.
// PV = mfma(V,P) -> O^T (col=q=l15). T13 defer-max with THR=8 (p <= 256).
__launch_bounds__(256)
__global__ void attn_fwd(const ushort* __restrict__ qkv,
                         const int* __restrict__ mask,
                         ushort* __restrict__ attn) {
  __shared__ ushort sK[2][64 * 64];
  __shared__ ushort sVT[2][64 * 64];   // [d][kv] rows=d, 16B-chunk XOR swizzle

  const int tid = threadIdx.x;
  const int lane = tid & 63;
  const int wid = tid >> 6;
  const int l15 = lane & 15;
  const int lg = lane >> 4;
  const int qt = blockIdx.x;   // 0..15
  const int bh = blockIdx.y;   // 0..63
  const int b = bh >> 4, h = bh & 15;

  const ushort* Qp  = qkv + (size_t)(bh * 3 + 0) * T_SEQ * DHEAD;
  const ushort* Kp  = qkv + (size_t)(bh * 3 + 1) * T_SEQ * DHEAD;
  const ushort* VTp = qkv + (size_t)(bh * 3 + 2) * T_SEQ * DHEAD;  // [64][2048]
  const int* mrow = mask + b * T_SEQ;

  const int qbase = qt * 128 + wid * 32;

  // Q fragments, pre-scaled by 0.125 * log2(e) -> S comes out in log2 units
  const float QSCALE = 0.18033688011112042f;
  short8 qf[2][2];
#pragma unroll
  for (int m = 0; m < 2; ++m)
#pragma unroll
    for (int ks = 0; ks < 2; ++ks) {
      short8 raw = *(const short8*)&Qp[(size_t)(qbase + m * 16 + l15) * 64 + ks * 32 + lg * 8];
#pragma unroll
      for (int e = 0; e < 8; ++e)
        qf[m][ks][e] = (short)f2bf(bf2f((ushort)raw[e]) * QSCALE);
    }

  float mrun[2] = {-1e30f, -1e30f};
  float lrun[2] = {0.f, 0.f};
  f32x4 oacc[2][4] = {};   // [m][dt] = O^T tile: row d=dt*16+lg*4+r, col q=m*16+l15

  auto STAGE = [&](int buf, int kt) {
    const int kb = kt * 64;
#pragma unroll
    for (int r2 = 0; r2 < 2; ++r2) {
      int c = r2 * 256 + tid;
      int row = c >> 3, ci = c & 7;
      int sb = (ci ^ (row & 7)) * 8;   // 16B-chunk source pre-swizzle
      gload_lds16(Kp + (size_t)(kb + row) * 64 + sb, &sK[buf][c * 8]);
      gload_lds16(VTp + (size_t)row * T_SEQ + kb + sb, &sVT[buf][c * 8]);
    }
  };

  STAGE(0, 0);
  __syncthreads();

  const int NT = T_SEQ / 64;
  for (int kt = 0; kt < NT; ++kt) {
    const int cur = kt & 1;
    int mv = mrow[kt * 64 + lane];          // issued early, consumed post-QK
    if (kt + 1 < NT) STAGE(cur ^ 1, kt + 1);

    // S^T = K (Q*scale)^T : st[n][m], lane holds S2[q=l15][kv = n*16+lg*4+r]
    f32x4 st[4][2] = {};
#pragma unroll
    for (int ks = 0; ks < 2; ++ks) {
      short8 kf[4];
#pragma unroll
      for (int n = 0; n < 4; ++n)
        kf[n] = *(const short8*)&sK[cur][(n * 16 + l15) * 64 + ((ks * 4 + lg) ^ (l15 & 7)) * 8];
      __builtin_amdgcn_s_setprio(1);
#pragma unroll
      for (int n = 0; n < 4; ++n)
#pragma unroll
        for (int m = 0; m < 2; ++m)
          st[n][m] = __builtin_amdgcn_mfma_f32_16x16x32_bf16(kf[n], qf[m][ks], st[n][m], 0, 0, 0);
      __builtin_amdgcn_s_setprio(0);
    }

    // key mask via wave bitmap
    unsigned long long km = __ballot(mv != 0);
#pragma unroll
    for (int n = 0; n < 4; ++n) {
      uint32_t k4 = (uint32_t)(km >> (n * 16 + lg * 4)) & 0xFu;
#pragma unroll
      for (int m = 0; m < 2; ++m)
#pragma unroll
        for (int r = 0; r < 4; ++r)
          if (!(k4 & (1u << r))) st[n][m][r] = -1e30f;
    }

    // online softmax, log2 domain; per-lane row (q=l15)
#pragma unroll
    for (int m = 0; m < 2; ++m) {
      // max over the 16 in-register values, max3-shaped
      float a0 = fmaxf(fmaxf(st[0][m][0], st[0][m][1]), fmaxf(st[0][m][2], st[0][m][3]));
      float a1 = fmaxf(fmaxf(st[1][m][0], st[1][m][1]), fmaxf(st[1][m][2], st[1][m][3]));
      float a2 = fmaxf(fmaxf(st[2][m][0], st[2][m][1]), fmaxf(st[2][m][2], st[2][m][3]));
      float a3 = fmaxf(fmaxf(st[3][m][0], st[3][m][1]), fmaxf(st[3][m][2], st[3][m][3]));
      float mx = fmaxf(fmaxf(a0, a1), fmaxf(a2, a3));
      mx = fmaxf(mx, __shfl_xor(mx, 16, 64));
      mx = fmaxf(mx, __shfl_xor(mx, 32, 64));

      // T13 defer-max: only rescale when some row grew past THR=8 (p <= 2^8)
      if (__any(mx > mrun[m] + 8.f)) {
        float mn = fmaxf(mrun[m], mx);
        float alpha = EXP2(mrun[m] - mn);
        mrun[m] = mn;
        lrun[m] *= alpha;
#pragma unroll
        for (int dt = 0; dt < 4; ++dt)
#pragma unroll
          for (int r = 0; r < 4; ++r) oacc[m][dt][r] *= alpha;
      }
      const float mcur = mrun[m];
      float rs = 0.f;
#pragma unroll
      for (int n = 0; n < 4; ++n)
#pragma unroll
        for (int r = 0; r < 4; ++r) {
          float p = EXP2(st[n][m][r] - mcur);
          st[n][m][r] = p;
          rs += p;
        }
      rs += __shfl_xor(rs, 16, 64);
      rs += __shfl_xor(rs, 32, 64);
      lrun[m] += rs;
    }

    // pack P -> bf16 A/B-frag (k-slot sigma: e<4 -> n=ks*2, e>=4 -> n=ks*2+1)
    short8 pa[2][2];
#pragma unroll
    for (int m = 0; m < 2; ++m)
#pragma unroll
      for (int ks = 0; ks < 2; ++ks)
#pragma unroll
        for (int e = 0; e < 4; ++e) {
          pa[m][ks][e]     = (short)f2bf(st[ks * 2][m][e]);
          pa[m][ks][4 + e] = (short)f2bf(st[ks * 2 + 1][m][e]);
        }

    // O^T += V^T * P^T : A = V-frag (rows d), B = P-frag (cols q)
#pragma unroll
    for (int ks = 0; ks < 2; ++ks)
#pragma unroll
      for (int dt = 0; dt < 4; ++dt) {
        const int row = dt * 16 + l15;
        const short4b v0 = *(const short4b*)&sVT[cur][row * 64 +
            (((ks * 4 + 0 + (lg >> 1)) ^ (l15 & 7)) * 8) + (lg & 1) * 4];
        const short4b v1 = *(const short4b*)&sVT[cur][row * 64 +
            (((ks * 4 + 2 + (lg >> 1)) ^ (l15 & 7)) * 8) + (lg & 1) * 4];
        short8 vf;
        vf[0] = v0[0]; vf[1] = v0[1]; vf[2] = v0[2]; vf[3] = v0[3];
        vf[4] = v1[0]; vf[5] = v1[1]; vf[6] = v1[2]; vf[7] = v1[3];
        __builtin_amdgcn_s_setprio(1);
#pragma unroll
        for (int m = 0; m < 2; ++m)
          oacc[m][dt] = __builtin_amdgcn_mfma_f32_16x16x32_bf16(vf, pa[m][ks], oacc[m][dt], 0, 0, 0);
        __builtin_amdgcn_s_setprio(0);
      }
    __syncthreads();
  }

  // epilogue: O^T layout -> packed 8B stores (d contiguous over r)
#pragma unroll
  for (int m = 0; m < 2; ++m) {
    float rl = 1.0f / lrun[m];
    int t = qbase + m * 16 + l15;
#pragma unroll
    for (int dt = 0; dt < 4; ++dt) {
      short4b ov;
#pragma unroll
      for (int r = 0; r < 4; ++r) ov[r] = (short)f2bf(oacc[m][dt][r] * rl);
      *(short4b*)&attn[(size_t)(b * T_SEQ + t) * DMODEL + h * DHEAD + dt * 16 + lg * 4] = ov;
    }
  }
}

// ---------------- launch ----------------
extern "C" void kernel_launch(void* const* d_in, const int* in_sizes, int n_in,
                              void* d_out, int out_size, void* d_ws, size_t ws_size,
                              hipStream_t stream) {
  (void)in_sizes; (void)n_in; (void)out_size; (void)ws_size;
  const float* x      = (const float*)d_in[0];  // [4,2048,1024]
  const int*   mask   = (const int*)d_in[1];    // [4,2048]
  const float* w_qkv  = (const float*)d_in[2];  // [3072,1024]
  const float* w_tail = (const float*)d_in[3];  // [1024,1024]
  const float* b_tail = (const float*)d_in[4];  // [1024]
  float* out = (float*)d_out;

  const size_t M = 4 * 2048;
  ushort* xb     = (ushort*)d_ws;                    // 8192*1024
  ushort* wqkvb  = xb + M * DMODEL;                  // 3072*1024
  ushort* wtailb = wqkvb + 3 * DMODEL * DMODEL;      // 1024*1024
  ushort* qkvb   = wtailb + DMODEL * DMODEL;         // 64*3*2048*64
  ushort* attnb  = qkvb + (size_t)64 * 3 * T_SEQ * DHEAD;  // 8192*1024

  {
    int n8 = (int)(M * DMODEL / 8);
    cvt_f32_bf16<<<n8 / 256, 256, 0, stream>>>(x, xb, n8);
  }
  {
    int n8 = 3 * DMODEL * DMODEL / 8;
    cvt_f32_bf16<<<n8 / 256, 256, 0, stream>>>(w_qkv, wqkvb, n8);
  }
  {
    int n8 = DMODEL * DMODEL / 8;
    cvt_f32_bf16<<<n8 / 256, 256, 0, stream>>>(w_tail, wtailb, n8);
  }

  // GEMM1: qkv = x @ w_qkv^T ; scatter Q,K [t][d], V [d][t]
  gemm_bt<0><<<dim3(M / 128, 3 * DMODEL / 128), 256, 0, stream>>>(
      xb, wqkvb, qkvb, nullptr, (int)M, 3 * DMODEL, DMODEL);

  // attention
  attn_fwd<<<dim3(T_SEQ / 128, 64), 256, 0, stream>>>(qkvb, mask, attnb);

  // GEMM2: out = attn @ w_tail^T + b_tail (fp32 out)
  gemm_bt<1><<<dim3(M / 128, DMODEL / 128), 256, 0, stream>>>(
      attnb, wtailb, out, b_tail, (int)M, DMODEL, DMODEL);
}